// Round 1
// baseline (1031.312 us; speedup 1.0000x reference)
//
#include <hip/hip_runtime.h>

// out = relu(x @ W1) @ W2
// x: [N, 155] fp32, W1: [155, 128] fp32, W2: [128, 3] fp32, out: [N, 3] fp32
// Layer 1 via bf16 MFMA 16x16x32 (fp32 accum), layer 2 fused in registers.

#define N_TOTAL 1048576
#define IN_DIM 155
#define HIDDEN 128
#define OUT_DIM 3
#define LDSK 168  // LDS k-stride for W1 (155 padded to 160, +8 => 2-way-free bank aliasing, 16B aligned rows)

typedef __attribute__((ext_vector_type(8))) short short8;      // 8 bf16 (4 VGPRs) - MFMA A/B frag
typedef __attribute__((ext_vector_type(4))) float floatx4;     // MFMA C/D frag
typedef __attribute__((ext_vector_type(4), aligned(4))) float float4u;  // 4-byte-aligned float4 (rows are 155 floats)

static __device__ __forceinline__ unsigned short f2bf(float f) {
  // round-to-nearest-even fp32 -> bf16 (inputs are finite normals)
  unsigned int u = __builtin_bit_cast(unsigned int, f);
  u += 0x7fffu + ((u >> 16) & 1u);
  return (unsigned short)(u >> 16);
}

__global__ __launch_bounds__(256) void fused_mlp_kernel(
    const float* __restrict__ x, const float* __restrict__ W1,
    const float* __restrict__ W2, float* __restrict__ out) {
  // W1 staged transposed: w1s[n * LDSK + k] = bf16(W1[k][n]); k in [155,160) zeroed.
  __shared__ __align__(16) unsigned short w1s[HIDDEN * LDSK];
  __shared__ float w2s[HIDDEN * OUT_DIM];

  const int tid = threadIdx.x;

  for (int idx = tid; idx < IN_DIM * HIDDEN; idx += 256) {
    const int k = idx >> 7;      // row of W1
    const int n = idx & 127;     // col of W1
    w1s[n * LDSK + k] = f2bf(W1[idx]);
  }
  // zero the k-pad (155..159); disjoint from the writes above
  for (int idx = tid; idx < HIDDEN * 8; idx += 256) {
    const int n = idx >> 3;
    const int k = 152 + (idx & 7);
    if (k >= IN_DIM) w1s[n * LDSK + k] = 0;
  }
  for (int idx = tid; idx < HIDDEN * OUT_DIM; idx += 256) w2s[idx] = W2[idx];
  __syncthreads();

  const int wave = tid >> 6;
  const int ln = tid & 15;          // lane&15: A row / B col / D col
  const int quad = (tid >> 4) & 3;  // lane>>4: k-group for A/B, row-group for D

  const int block_row0 = blockIdx.x * 256;

  for (int tile = 0; tile < 4; ++tile) {
    const int row0 = block_row0 + wave * 64 + tile * 16;
    floatx4 acc[8];
#pragma unroll
    for (int t = 0; t < 8; ++t) acc[t] = (floatx4)0.f;

    const float* xr = x + (size_t)(row0 + ln) * IN_DIM;

#pragma unroll
    for (int s = 0; s < 5; ++s) {
      const int kb = s * 32 + quad * 8;  // this lane's 8-wide k chunk
      // ---- A fragment: x[row0+ln][kb .. kb+7] as bf16 ----
      float av[8];
      if (s == 4 && quad == 3) {
        // cols 152..159: 152..154 valid, rest zero (B pad is zero anyway, but avoid OOB reads)
#pragma unroll
        for (int j = 0; j < 8; ++j) {
          const int k = kb + j;
          av[j] = (k < IN_DIM) ? xr[k] : 0.f;
        }
      } else {
        const float4u* p = reinterpret_cast<const float4u*>(xr + kb);
        const float4u v0 = p[0];
        const float4u v1 = p[1];
        av[0] = v0.x; av[1] = v0.y; av[2] = v0.z; av[3] = v0.w;
        av[4] = v1.x; av[5] = v1.y; av[6] = v1.z; av[7] = v1.w;
      }
      short8 a;
#pragma unroll
      for (int j = 0; j < 8; ++j) a[j] = (short)f2bf(av[j]);

      // ---- 8 col-tiles of W1 ----
#pragma unroll
      for (int t = 0; t < 8; ++t) {
        const short8 b =
            *reinterpret_cast<const short8*>(&w1s[(t * 16 + ln) * LDSK + kb]);
        acc[t] = __builtin_amdgcn_mfma_f32_16x16x32_bf16(a, b, acc[t], 0, 0, 0);
      }
    }

    // ---- layer 2: out[row][c] = sum_k relu(h[row][k]) * W2[k][c] ----
    // lane holds h[row0 + quad*4 + r][16*t + ln] in acc[t][r]
    float part[4][3];
#pragma unroll
    for (int r = 0; r < 4; ++r)
#pragma unroll
      for (int c = 0; c < 3; ++c) part[r][c] = 0.f;

#pragma unroll
    for (int t = 0; t < 8; ++t) {
      const int k = t * 16 + ln;
      const float w0 = w2s[k * 3 + 0];
      const float w1v = w2s[k * 3 + 1];
      const float w2v = w2s[k * 3 + 2];
#pragma unroll
      for (int r = 0; r < 4; ++r) {
        const float hv = fmaxf(acc[t][r], 0.f);
        part[r][0] = fmaf(hv, w0, part[r][0]);
        part[r][1] = fmaf(hv, w1v, part[r][1]);
        part[r][2] = fmaf(hv, w2v, part[r][2]);
      }
    }

    // reduce the k-partials across the 16 lanes of each quad
#pragma unroll
    for (int off = 1; off < 16; off <<= 1) {
#pragma unroll
      for (int r = 0; r < 4; ++r)
#pragma unroll
        for (int c = 0; c < 3; ++c)
          part[r][c] += __shfl_xor(part[r][c], off, 16);
    }

    // lanes 0..11 of each quad each write one of the 12 outputs
#pragma unroll
    for (int r = 0; r < 4; ++r)
#pragma unroll
      for (int c = 0; c < 3; ++c)
        if (ln == r * 3 + c)
          out[(size_t)(row0 + quad * 4 + r) * 3 + c] = part[r][c];
  }
}

extern "C" void kernel_launch(void* const* d_in, const int* in_sizes, int n_in,
                              void* d_out, int out_size, void* d_ws, size_t ws_size,
                              hipStream_t stream) {
  const float* x = (const float*)d_in[0];
  const float* W1 = (const float*)d_in[1];
  const float* W2 = (const float*)d_in[2];
  float* out = (float*)d_out;
  fused_mlp_kernel<<<dim3(N_TOTAL / 256), dim3(256), 0, stream>>>(x, W1, W2, out);
}

// Round 2
// 887.412 us; speedup vs baseline: 1.1622x; 1.1622x over previous
//
#include <hip/hip_runtime.h>

// out = relu(x @ W1) @ W2
// x: [N,155] fp32, W1: [155,128] fp32, W2: [128,3] fp32, out: [N,3] fp32.
// v2: coalesced flat float4 global loads -> register prefetch -> bf16 LDS tile,
//     MFMA 16x16x32 layer 1 (32 rows/wave per k-sweep), register W2 epilogue.

#define N_TOTAL 1048576
#define IN_DIM 155
#define HIDDEN 128
#define ROWS_PER_BLOCK 1024
#define TILE_ROWS 128
#define NTILES 8                       // ROWS_PER_BLOCK / TILE_ROWS
#define XK 168                         // LDS k-stride (bf16): 336B rows, 16B aligned, 2-way-free banks
#define TILE_ELEMS (TILE_ROWS * IN_DIM)  // 19840 floats
#define TILE_F4 (TILE_ELEMS / 4)         // 4960 float4s
#define F4_PER_THREAD 20                 // ceil(4960 / 256)

typedef __attribute__((ext_vector_type(4))) float fvec4;
typedef __attribute__((ext_vector_type(8))) short short8;   // 8 bf16 (4 VGPRs) MFMA A/B frag
typedef __attribute__((ext_vector_type(4))) float floatx4;  // MFMA C/D frag

static __device__ __forceinline__ unsigned short f2bf(float f) {
  // round-to-nearest-even fp32 -> bf16 (inputs are finite normals)
  unsigned int u = __builtin_bit_cast(unsigned int, f);
  u += 0x7fffu + ((u >> 16) & 1u);
  return (unsigned short)(u >> 16);
}

static __device__ __forceinline__ void epilogue_16rows(
    const floatx4* acc, const float w2r[8][3], int ln, int quad,
    float* __restrict__ out, size_t row0) {
  // acc[t][r] = h[row0 + quad*4 + r][16*t + ln]
  float part[4][3];
#pragma unroll
  for (int r = 0; r < 4; ++r)
#pragma unroll
    for (int c = 0; c < 3; ++c) part[r][c] = 0.f;

#pragma unroll
  for (int t = 0; t < 8; ++t) {
#pragma unroll
    for (int r = 0; r < 4; ++r) {
      const float hv = fmaxf(acc[t][r], 0.f);
      part[r][0] = fmaf(hv, w2r[t][0], part[r][0]);
      part[r][1] = fmaf(hv, w2r[t][1], part[r][1]);
      part[r][2] = fmaf(hv, w2r[t][2], part[r][2]);
    }
  }
  // reduce k-partials across the 16 lanes of each quad
#pragma unroll
  for (int off = 1; off < 16; off <<= 1) {
#pragma unroll
    for (int r = 0; r < 4; ++r)
#pragma unroll
      for (int c = 0; c < 3; ++c) part[r][c] += __shfl_xor(part[r][c], off, 16);
  }
  // lanes 0..11 of each quad write the 12 outputs
#pragma unroll
  for (int r = 0; r < 4; ++r)
#pragma unroll
    for (int c = 0; c < 3; ++c)
      if (ln == r * 3 + c) out[(row0 + quad * 4 + r) * 3 + c] = part[r][c];
}

__global__ __launch_bounds__(256, 1) void fused_mlp_kernel(
    const float* __restrict__ x, const float* __restrict__ W1,
    const float* __restrict__ W2, float* __restrict__ out) {
  __shared__ __align__(16) unsigned short w1s[HIDDEN * XK];  // W1^T bf16, k-padded
  __shared__ __align__(16) unsigned short xs[TILE_ROWS * XK];  // x tile bf16, k-padded

  const int tid = threadIdx.x;
  const int ln = tid & 15;
  const int quad = (tid >> 4) & 3;
  const int wave = tid >> 6;

  // ---- stage W1^T as bf16 into LDS ----
  for (int idx = tid; idx < IN_DIM * HIDDEN; idx += 256) {
    const int k = idx >> 7;
    const int n = idx & 127;
    w1s[n * XK + k] = f2bf(W1[idx]);
  }
  for (int idx = tid; idx < HIDDEN * 8; idx += 256) {  // zero k-pad 155..159
    const int n = idx >> 3;
    const int k = 152 + (idx & 7);
    if (k >= IN_DIM) w1s[n * XK + k] = 0;
  }
  // zero xs k-pad cols 155..159 (never overwritten by staging)
  for (int idx = tid; idx < TILE_ROWS * 5; idx += 256) {
    const int r = idx / 5;
    const int c = IN_DIM + (idx - r * 5);
    xs[r * XK + c] = 0;
  }
  // ---- W2 into registers (L2-resident, once per block) ----
  float w2r[8][3];
#pragma unroll
  for (int t = 0; t < 8; ++t)
#pragma unroll
    for (int c = 0; c < 3; ++c) w2r[t][c] = W2[(t * 16 + ln) * 3 + c];
  __syncthreads();

  const size_t block_e0 = (size_t)blockIdx.x * ROWS_PER_BLOCK * IN_DIM;

  // ---- prefetch tile 0 (flat coalesced float4, 16B aligned) ----
  fvec4 pre[F4_PER_THREAD];
  {
    const fvec4* src = reinterpret_cast<const fvec4*>(x + block_e0);
#pragma unroll
    for (int i = 0; i < F4_PER_THREAD; ++i) {
      const int f = tid + i * 256;
      if (f < TILE_F4) pre[i] = src[f];
    }
  }

  for (int t = 0; t < NTILES; ++t) {
    // ---- convert prefetched tile -> xs (bf16, padded rows) ----
#pragma unroll
    for (int i = 0; i < F4_PER_THREAD; ++i) {
      const int f = tid + i * 256;
      if (f < TILE_F4) {
        const int e0 = f * 4;
        const int r = e0 / IN_DIM;
        const int c = e0 - r * IN_DIM;
#pragma unroll
        for (int j = 0; j < 4; ++j) {
          const int cc = c + j;
          const int wrap = (cc >= IN_DIM);
          xs[(r + wrap) * XK + (cc - wrap * IN_DIM)] = f2bf(pre[i][j]);
        }
      }
    }
    __syncthreads();

    // ---- issue next tile's loads (stay in flight during compute) ----
    if (t + 1 < NTILES) {
      const fvec4* src = reinterpret_cast<const fvec4*>(
          x + block_e0 + (size_t)(t + 1) * TILE_ELEMS);
#pragma unroll
      for (int i = 0; i < F4_PER_THREAD; ++i) {
        const int f = tid + i * 256;
        if (f < TILE_F4) pre[i] = src[f];
      }
    }

    // ---- layer 1: 32 rows per wave (2 sub-tiles of 16), shared B-frags ----
    floatx4 acc0[8], acc1[8];
#pragma unroll
    for (int c = 0; c < 8; ++c) {
      acc0[c] = (floatx4)0.f;
      acc1[c] = (floatx4)0.f;
    }
    const int rbase = wave * 32;
#pragma unroll
    for (int s = 0; s < 5; ++s) {
      const int kb = s * 32 + quad * 8;
      const short8 a0 = *reinterpret_cast<const short8*>(&xs[(rbase + ln) * XK + kb]);
      const short8 a1 = *reinterpret_cast<const short8*>(&xs[(rbase + 16 + ln) * XK + kb]);
#pragma unroll
      for (int t8 = 0; t8 < 8; ++t8) {
        const short8 b = *reinterpret_cast<const short8*>(&w1s[(t8 * 16 + ln) * XK + kb]);
        acc0[t8] = __builtin_amdgcn_mfma_f32_16x16x32_bf16(a0, b, acc0[t8], 0, 0, 0);
        acc1[t8] = __builtin_amdgcn_mfma_f32_16x16x32_bf16(a1, b, acc1[t8], 0, 0, 0);
      }
    }

    // ---- layer 2 + store ----
    const size_t row0 =
        (size_t)blockIdx.x * ROWS_PER_BLOCK + (size_t)t * TILE_ROWS + wave * 32;
    epilogue_16rows(acc0, w2r, ln, quad, out, row0);
    epilogue_16rows(acc1, w2r, ln, quad, out, row0 + 16);
    __syncthreads();  // all waves done reading xs before next overwrite
  }
}

extern "C" void kernel_launch(void* const* d_in, const int* in_sizes, int n_in,
                              void* d_out, int out_size, void* d_ws, size_t ws_size,
                              hipStream_t stream) {
  const float* x = (const float*)d_in[0];
  const float* W1 = (const float*)d_in[1];
  const float* W2 = (const float*)d_in[2];
  float* out = (float*)d_out;
  fused_mlp_kernel<<<dim3(N_TOTAL / ROWS_PER_BLOCK), dim3(256), 0, stream>>>(x, W1, W2, out);
}